// Round 11
// baseline (282.084 us; speedup 1.0000x reference)
//
#include <hip/hip_runtime.h>
#include <hip/hip_bf16.h>
#include <math.h>

// FrequencySelfAttention3: B=8, C=128, H=W=64 (N=4096 tokens).
// ifft2(|F|·w_c·e^{i·angle F}) = w_c·x  -> FFT branch is a per-channel scale.
// R18: R17's cooperative fusion failed (absmax=max|ref| => kernel likely
// never ran: hipLaunchCooperativeKernel incompatible with harness graph
// capture). Same goal, harness-safe mechanism: TICKET-FUSED merge. The
// flash->merge dep is pairwise: merge tiles (b,2qt..2qt+1) need exactly
// flash WGs (b,half=0,qt) and (b,half=1,qt). Each flash WG: write partials,
// __threadfence (release), atomicAdd ticket[b*32+qt]; SECOND arriver fences
// (acquire) and merges its two tiles in the tail, reusing flash LDS.
// Removes the merge launch + drain + cold Op re-read. R12 proved
// device-scope atomics work cross-XCD on this harness. Proj = R16-exact
// (passed); flash body = R11/R16-exact (measured 100us, VGPR 104).

typedef __bf16 bf16;
typedef _Float16 f16;
typedef __bf16 bf16x8 __attribute__((ext_vector_type(8)));
typedef __bf16 bf16x4 __attribute__((ext_vector_type(4)));
typedef __bf16 bf16x2 __attribute__((ext_vector_type(2)));
typedef _Float16 f16x8 __attribute__((ext_vector_type(8)));
typedef float  f32x4  __attribute__((ext_vector_type(4)));
typedef unsigned int u32x4 __attribute__((ext_vector_type(4)));

#define MFMA16(a, b, c) __builtin_amdgcn_mfma_f32_16x16x32_bf16((a), (b), (c), 0, 0, 0)

static constexpr int BATCH = 8;
static constexpr int CH    = 128;
static constexpr int NTOK  = 4096;
static constexpr int XS    = 136;   // proj stage stride (bf16 elems)
static constexpr int VS    = 72;    // proj V-stage stride
static constexpr int PS    = 72;    // flash P stride (144 B, 16B-aligned)
static constexpr int MS    = 136;   // merge O row stride
static constexpr float FIXM = 8.0f; // fixed max, exp2 domain (|S*log2e| <~ 7)

// fp32 row -> bf16x8 fragment with scale (weights are L2-hot)
__device__ inline bf16x8 cvt8(const float* p, float s) {
  f32x4 a = *(const f32x4*)p;
  f32x4 b = *(const f32x4*)(p + 4);
  bf16x8 r;
  #pragma unroll
  for (int i = 0; i < 4; ++i) { r[i] = (bf16)(a[i] * s); r[4 + i] = (bf16)(b[i] * s); }
  return r;
}

// ---------------- kernel 1: QKV projections (R16-exact) --------------------
__global__ __launch_bounds__(512) void proj_kernel(
    const float* __restrict__ x, const float* __restrict__ fw,
    const float* __restrict__ wq, const float* __restrict__ wk,
    const float* __restrict__ wv,
    const float* __restrict__ bq, const float* __restrict__ bk,
    const float* __restrict__ bv,
    bf16* __restrict__ Qt, bf16* __restrict__ Kt, bf16* __restrict__ Vt,
    float qscale)
{
  const int wg = blockIdx.x;
  const int b = wg >> 6, tile = wg & 63;
  const int t = threadIdx.x;
  const int w = t >> 6, lane = t & 63, quad = lane >> 4, l15 = lane & 15;

  __shared__ bf16 stage[128 * VS];      // 18432 B; aliases Xt[64][XS] (17408)

  const float* xb = x + (size_t)b * CH * NTOK + tile * 64;
  #pragma unroll
  for (int i = 0; i < 8; ++i) {
    int c = (i * 8 + w) * 2;            // channel pair
    float f0 = fw[c], f1 = fw[c + 1];
    float x0 = xb[(size_t)c * NTOK + lane] * f0;
    float x1 = xb[(size_t)(c + 1) * NTOK + lane] * f1;
    bf16x2 pk; pk.x = (bf16)x0; pk.y = (bf16)x1;
    *(bf16x2*)(&stage[lane * XS + c]) = pk;
  }
  __syncthreads();

  bf16x8 xfrag[4][4];
  #pragma unroll
  for (int st = 0; st < 4; ++st)
    #pragma unroll
    for (int ks = 0; ks < 4; ++ks)
      xfrag[st][ks] = *(const bf16x8*)(&stage[(st * 16 + l15) * XS + ks * 32 + quad * 8]);

  const size_t wrow = (size_t)(w * 16 + l15) * CH;
  const int tokb = tile * 64;
  __syncthreads();                      // all xfrag in regs; stage reusable

  // ---- Q ----
  {
    bf16x8 qw[4];
    #pragma unroll
    for (int ks = 0; ks < 4; ++ks) qw[ks] = cvt8(wq + wrow + ks * 32 + quad * 8, qscale);
    f32x4 acc[4];
    #pragma unroll
    for (int st = 0; st < 4; ++st) acc[st] = (f32x4){0.f, 0.f, 0.f, 0.f};
    #pragma unroll
    for (int ks = 0; ks < 4; ++ks)
      #pragma unroll
      for (int st = 0; st < 4; ++st)
        acc[st] = MFMA16(qw[ks], xfrag[st][ks], acc[st]);
    float bias[4];
    #pragma unroll
    for (int r = 0; r < 4; ++r) bias[r] = bq[w * 16 + quad * 4 + r] * qscale;
    #pragma unroll
    for (int st = 0; st < 4; ++st) {
      bf16x4 o;
      #pragma unroll
      for (int r = 0; r < 4; ++r) o[r] = (bf16)(acc[st][r] + bias[r]);
      *(bf16x4*)(&stage[(st * 16 + l15) * XS + w * 16 + quad * 4]) = o;
    }
    __syncthreads();
    #pragma unroll
    for (int p = 0; p < 2; ++p) {
      int idx = p * 512 + t, row = idx >> 4, ch = (idx & 15) * 8;
      u32x4 d = *(const u32x4*)(&stage[row * XS + ch]);
      *(u32x4*)(&Qt[((size_t)b * NTOK + tokb + row) * CH + ch]) = d;
    }
    __syncthreads();
  }
  // ---- K ----
  {
    bf16x8 kw[4];
    #pragma unroll
    for (int ks = 0; ks < 4; ++ks) kw[ks] = cvt8(wk + wrow + ks * 32 + quad * 8, 1.0f);
    f32x4 acc[4];
    #pragma unroll
    for (int st = 0; st < 4; ++st) acc[st] = (f32x4){0.f, 0.f, 0.f, 0.f};
    #pragma unroll
    for (int ks = 0; ks < 4; ++ks)
      #pragma unroll
      for (int st = 0; st < 4; ++st)
        acc[st] = MFMA16(kw[ks], xfrag[st][ks], acc[st]);
    float bias[4];
    #pragma unroll
    for (int r = 0; r < 4; ++r) bias[r] = bk[w * 16 + quad * 4 + r];
    #pragma unroll
    for (int st = 0; st < 4; ++st) {
      bf16x4 o;
      #pragma unroll
      for (int r = 0; r < 4; ++r) o[r] = (bf16)(acc[st][r] + bias[r]);
      *(bf16x4*)(&stage[(st * 16 + l15) * XS + w * 16 + quad * 4]) = o;
    }
    __syncthreads();
    #pragma unroll
    for (int p = 0; p < 2; ++p) {
      int idx = p * 512 + t, row = idx >> 4, ch = (idx & 15) * 8;
      u32x4 d = *(const u32x4*)(&stage[row * XS + ch]);
      *(u32x4*)(&Kt[((size_t)b * NTOK + tokb + row) * CH + ch]) = d;
    }
    __syncthreads();
  }
  // ---- V ----
  {
    bf16x8 vw[4];
    #pragma unroll
    for (int ks = 0; ks < 4; ++ks) vw[ks] = cvt8(wv + wrow + ks * 32 + quad * 8, 1.0f);
    f32x4 acc[4];
    #pragma unroll
    for (int st = 0; st < 4; ++st) acc[st] = (f32x4){0.f, 0.f, 0.f, 0.f};
    #pragma unroll
    for (int ks = 0; ks < 4; ++ks)
      #pragma unroll
      for (int st = 0; st < 4; ++st)
        acc[st] = MFMA16(xfrag[st][ks], vw[ks], acc[st]);
    float bias = bv[w * 16 + l15];
    #pragma unroll
    for (int st = 0; st < 4; ++st) {
      bf16x4 o;
      #pragma unroll
      for (int r = 0; r < 4; ++r) o[r] = (bf16)(acc[st][r] + bias);
      *(bf16x4*)(&stage[(w * 16 + l15) * VS + st * 16 + quad * 4]) = o;
    }
    __syncthreads();
    #pragma unroll
    for (int p = 0; p < 2; ++p) {
      int idx = p * 512 + t, row = idx >> 3, tk = (idx & 7) * 8;
      u32x4 d = *(const u32x4*)(&stage[row * VS + tk]);
      *(u32x4*)(&Vt[((size_t)b * CH + row) * NTOK + tokb + tk]) = d;
    }
  }
}

// ---------------- kernel 2: flash partial + ticket-fused merge -------------
// Grid 512 = b(8) x half(2) x qt128(32). Flash body R11-exact. Second WG
// to finish a (b,qt) pair merges tiles 2qt,2qt+1 in its tail (LDS reused).
__global__ __launch_bounds__(256, 2) void flash_merge_kernel(
    const bf16* __restrict__ Qt, const bf16* __restrict__ Kt,
    const bf16* __restrict__ Vt, f16* __restrict__ Op, float* __restrict__ Lp,
    const float* __restrict__ wo, const float* __restrict__ bo,
    float* __restrict__ out, unsigned int* __restrict__ ticket)
{
  __shared__ __align__(16) char ldsbuf[51264];
  bf16* ldsK = (bf16*)ldsbuf;            // [64][128], 16B-block ^= row&7
  bf16* ldsV = (bf16*)(ldsbuf + 16384);  // [128][64], 16B-block ^= row&7
  bf16* ldsP = (bf16*)(ldsbuf + 32768);  // per-wave [32][PS] (18432 B)
  unsigned int* s_flag = (unsigned int*)(ldsbuf + 51200);

  const int wg = blockIdx.x;
  const int b = wg >> 6, half = (wg >> 5) & 1, qt = wg & 31;
  const int t = threadIdx.x;
  const int w = t >> 6, lane = t & 63, quad = lane >> 4, l15 = lane & 15;
  const int swz = l15 & 7;

  bf16x8 qfrag[2][4];
  #pragma unroll
  for (int s2 = 0; s2 < 2; ++s2) {
    const bf16* qb = Qt + ((size_t)b * NTOK + qt * 128 + w * 32 + s2 * 16 + l15) * CH;
    #pragma unroll
    for (int ks = 0; ks < 4; ++ks)
      qfrag[s2][ks] = *(const bf16x8*)(qb + ks * 32 + quad * 8);
  }

  f32x4 o_acc[2][8];
  #pragma unroll
  for (int s2 = 0; s2 < 2; ++s2)
    #pragma unroll
    for (int nt = 0; nt < 8; ++nt) o_acc[s2][nt] = (f32x4){0.f, 0.f, 0.f, 0.f};
  float lsum[2] = {0.f, 0.f};

  const bf16* kb = Kt + ((size_t)b * NTOK + half * 2048) * CH;
  const bf16* vb = Vt + (size_t)b * CH * NTOK + half * 2048;
  bf16* Pw = ldsP + w * 32 * PS;

  const bf16* kg[4]; bf16* kl[4];
  const bf16* vg[4]; bf16* vl[4];
  #pragma unroll
  for (int i = 0; i < 4; ++i) {
    int idx = t + i * 256;
    { int row = idx >> 4, cb = idx & 15;
      kg[i] = kb + (size_t)idx * 8;
      kl[i] = &ldsK[row * 128 + ((cb ^ (row & 7)) * 8)]; }
    { int row = idx >> 3, cb = idx & 7;
      vg[i] = vb + (size_t)row * NTOK + cb * 8;
      vl[i] = &ldsV[row * 64 + ((cb ^ (row & 7)) * 8)]; }
  }

  // async-STAGE prologue: tile 0 -> registers (T14)
  u32x4 rk[4], rv[4];
  #pragma unroll
  for (int i = 0; i < 4; ++i) {
    rk[i] = *(const u32x4*)kg[i];
    rv[i] = *(const u32x4*)vg[i];
    kg[i] += 64 * CH;
    vg[i] += 64;
  }

  for (int kt = 0; kt < 32; ++kt) {
    __syncthreads();
    #pragma unroll
    for (int i = 0; i < 4; ++i) {       // regs -> LDS (loads landed long ago)
      *(u32x4*)kl[i] = rk[i];
      *(u32x4*)vl[i] = rv[i];
    }
    __syncthreads();

    if (kt < 31) {                      // prefetch next tile under compute
      #pragma unroll
      for (int i = 0; i < 4; ++i) {
        rk[i] = *(const u32x4*)kg[i];
        rv[i] = *(const u32x4*)vg[i];
        kg[i] += 64 * CH;
        vg[i] += 64;
      }
    }

    // S^T = K Q^T (qscale*L2E folded into Wq)
    #pragma unroll
    for (int mt = 0; mt < 4; ++mt) {
      f32x4 s[2];
      s[0] = (f32x4){0.f, 0.f, 0.f, 0.f};
      s[1] = (f32x4){0.f, 0.f, 0.f, 0.f};
      #pragma unroll
      for (int ks = 0; ks < 4; ++ks) {
        bf16x8 kfr = *(const bf16x8*)(&ldsK[(mt * 16 + l15) * 128 + (((ks * 4 + quad) ^ swz) * 8)]);
        s[0] = MFMA16(kfr, qfrag[0][ks], s[0]);
        s[1] = MFMA16(kfr, qfrag[1][ks], s[1]);
      }
      #pragma unroll
      for (int s2 = 0; s2 < 2; ++s2) {
        f32x4 v = s[s2];
        bf16x4 pk;
        float ps = 0.f;
        #pragma unroll
        for (int r = 0; r < 4; ++r) {
          float p = exp2f(v[r] - FIXM);
          ps += p;
          pk[r] = (bf16)p;
        }
        lsum[s2] += ps;
        *(bf16x4*)(&Pw[(s2 * 16 + l15) * PS + mt * 16 + quad * 4]) = pk;
      }
    }
    // P wave-private: wave-internal lgkmcnt orders write->read

    bf16x8 pfrag[2][2];
    #pragma unroll
    for (int s2 = 0; s2 < 2; ++s2)
      #pragma unroll
      for (int c = 0; c < 2; ++c)
        pfrag[s2][c] = *(const bf16x8*)(&Pw[(s2 * 16 + l15) * PS + c * 32 + quad * 8]);

    #pragma unroll
    for (int k2 = 0; k2 < 2; ++k2)
      #pragma unroll
      for (int nt = 0; nt < 8; ++nt) {
        bf16x8 vfr = *(const bf16x8*)(&ldsV[(nt * 16 + l15) * 64 + (((k2 * 4 + quad) ^ swz) * 8)]);
        o_acc[0][nt] = MFMA16(pfrag[0][k2], vfr, o_acc[0][nt]);
        o_acc[1][nt] = MFMA16(pfrag[1][k2], vfr, o_acc[1][nt]);
      }
  }

  // write unnormalized partial O (fp16) + partial row sums
  const size_t obase = ((size_t)(b * 2 + half) * NTOK + qt * 128 + w * 32) * CH;
  #pragma unroll
  for (int s2 = 0; s2 < 2; ++s2)
    #pragma unroll
    for (int nt = 0; nt < 8; ++nt)
      #pragma unroll
      for (int r = 0; r < 4; ++r) {
        int row = s2 * 16 + quad * 4 + r;
        Op[obase + (size_t)row * CH + nt * 16 + l15] = (f16)o_acc[s2][nt][r];
      }
  #pragma unroll
  for (int s2 = 0; s2 < 2; ++s2) {
    float v = lsum[s2];
    v += __shfl_xor(v, 16);
    v += __shfl_xor(v, 32);
    if (quad == 0)
      Lp[(size_t)(b * 2 + half) * NTOK + qt * 128 + w * 32 + s2 * 16 + l15] = v;
  }

  // ---- ticket: second arriver for (b,qt) merges tiles 2qt, 2qt+1 ----------
  __threadfence();                       // release: partials visible device-wide
  if (t == 0) *s_flag = atomicAdd(&ticket[b * 32 + qt], 1u);
  __syncthreads();                       // broadcast flag; LDS reads all done
  if (*s_flag != 1u) return;             // first arriver exits
  __threadfence();                       // acquire: other half's partials

  bf16* ldsO = (bf16*)ldsbuf;            // [64][MS] = 17408 B (over ldsK/V)
  #pragma unroll
  for (int j = 0; j < 2; ++j) {
    const int tile = qt * 2 + j;
    const f16* o0 = Op + ((size_t)(b * 2 + 0) * NTOK + tile * 64) * CH;
    const f16* o1 = Op + ((size_t)(b * 2 + 1) * NTOK + tile * 64) * CH;
    const float* lp0 = Lp + (size_t)(b * 2 + 0) * NTOK + tile * 64;
    const float* lp1 = Lp + (size_t)(b * 2 + 1) * NTOK + tile * 64;

    #pragma unroll
    for (int i = 0; i < 4; ++i) {
      int idx = t + i * 256;
      int row = idx >> 4, cb = idx & 15;
      float inv = 1.0f / (lp0[row] + lp1[row]);
      f16x8 a0 = *(const f16x8*)(o0 + (size_t)row * CH + cb * 8);
      f16x8 a1 = *(const f16x8*)(o1 + (size_t)row * CH + cb * 8);
      bf16 tmp[8];
      #pragma unroll
      for (int jj = 0; jj < 8; ++jj)
        tmp[jj] = (bf16)(((float)a0[jj] + (float)a1[jj]) * inv);
      *(u32x4*)(&ldsO[row * MS + cb * 8]) = *(u32x4*)tmp;
    }
    __syncthreads();

    #pragma unroll
    for (int mi = 0; mi < 2; ++mi) {
      int mt = w * 2 + mi;
      f32x4 facc[4];
      #pragma unroll
      for (int nt = 0; nt < 4; ++nt) facc[nt] = (f32x4){0.f, 0.f, 0.f, 0.f};
      #pragma unroll
      for (int ks = 0; ks < 4; ++ks) {
        bf16x8 afr = cvt8(wo + (size_t)(mt * 16 + l15) * CH + ks * 32 + quad * 8, 1.0f);
        #pragma unroll
        for (int nt = 0; nt < 4; ++nt) {
          bf16x8 bfr = *(const bf16x8*)(&ldsO[(nt * 16 + l15) * MS + ks * 32 + quad * 8]);
          facc[nt] = MFMA16(afr, bfr, facc[nt]);
        }
      }
      #pragma unroll
      for (int nt = 0; nt < 4; ++nt) {
        int n = tile * 64 + nt * 16 + l15;
        #pragma unroll
        for (int r = 0; r < 4; ++r) {
          int o = mt * 16 + quad * 4 + r;
          out[((size_t)b * CH + o) * NTOK + n] = facc[nt][r] + bo[o];
        }
      }
    }
    __syncthreads();                     // before next j overwrites ldsO
  }
}

// ---------------- launch ---------------------------------------------------
extern "C" void kernel_launch(void* const* d_in, const int* in_sizes, int n_in,
                              void* d_out, int out_size, void* d_ws, size_t ws_size,
                              hipStream_t stream)
{
  const float* x  = (const float*)d_in[0];
  const float* fw = (const float*)d_in[1];
  const float* wq = (const float*)d_in[2];
  const float* bq = (const float*)d_in[3];
  const float* wk = (const float*)d_in[4];
  const float* bk = (const float*)d_in[5];
  const float* wv = (const float*)d_in[6];
  const float* bv = (const float*)d_in[7];
  const float* wo = (const float*)d_in[8];
  const float* bo = (const float*)d_in[9];
  float* out = (float*)d_out;

  char* ws = (char*)d_ws;
  bf16*  Qt  = (bf16*)ws;                              // 8 MB
  bf16*  Kt  = Qt + (size_t)BATCH * NTOK * CH;         // 8 MB
  bf16*  Vt  = Kt + (size_t)BATCH * NTOK * CH;         // 8 MB
  f16*   Op  = (f16*)(ws + 3ull * 8388608);            // 16 MB: [2B][N][C] fp16
  float* Lp  = (float*)((char*)Op + 16777216);         // 256 KB
  unsigned int* ticket = (unsigned int*)((char*)Lp + 262144);  // 1 KB

  hipMemsetAsync(ticket, 0, 256 * sizeof(unsigned int), stream);

  // 1/sqrt(128) * log2(e): exp2-domain scale folded into Wq/bq
  const float qscale = 0.08838834764831845f * 1.44269504f;

  proj_kernel<<<512, 512, 0, stream>>>(x, fw, wq, wk, wv,
                                       bq, bk, bv, Qt, Kt, Vt, qscale);
  flash_merge_kernel<<<512, 256, 0, stream>>>(Qt, Kt, Vt, Op, Lp,
                                              wo, bo, out, ticket);
}

// Round 12
// 197.504 us; speedup vs baseline: 1.4282x; 1.4282x over previous
//
#include <hip/hip_runtime.h>
#include <hip/hip_bf16.h>
#include <math.h>

// FrequencySelfAttention3: B=8, C=128, H=W=64 (N=4096 tokens).
// ifft2(|F|·w_c·e^{i·angle F}) = w_c·x  -> FFT branch is a per-channel scale.
// R19: plumbing arc closed (R18: in-kernel cross-XCD merge = +97us vs 7us
// standalone launch -- kernel-boundary flush beats in-kernel fences; merge
// is only ~7us, so the "invisible" ~92us = proj + launch overhead). Back to
// the R16 3-kernel base (192.0us). Target: flash's VALUBusy 42% > MfmaUtil
// 28.6% -- the VALU pipe is the top consumer. (1) All swizzled LDS read/
// write addresses are loop-invariant per lane but were recomputed every
// kt-iter; now hoisted to base pointers + compile-time offset: immediates
// (mt stride 4096B, nt 2048B, all <64K). (2) T5 s_setprio(1) around MFMA
// clusters (m191: +4-7% attn with independent co-resident WGs; our 2 WG/CU
// are unsynchronized). Proj/merge = R16-exact.

typedef __bf16 bf16;
typedef _Float16 f16;
typedef __bf16 bf16x8 __attribute__((ext_vector_type(8)));
typedef __bf16 bf16x4 __attribute__((ext_vector_type(4)));
typedef __bf16 bf16x2 __attribute__((ext_vector_type(2)));
typedef _Float16 f16x8 __attribute__((ext_vector_type(8)));
typedef float  f32x4  __attribute__((ext_vector_type(4)));
typedef unsigned int u32x4 __attribute__((ext_vector_type(4)));

#define MFMA16(a, b, c) __builtin_amdgcn_mfma_f32_16x16x32_bf16((a), (b), (c), 0, 0, 0)

static constexpr int BATCH = 8;
static constexpr int CH    = 128;
static constexpr int NTOK  = 4096;
static constexpr int XS    = 136;   // proj stage stride (bf16 elems)
static constexpr int VS    = 72;    // proj V-stage stride
static constexpr int PS    = 72;    // flash P stride (144 B, 16B-aligned)
static constexpr int MS    = 136;   // merge O row stride
static constexpr float FIXM = 8.0f; // fixed max, exp2 domain (|S*log2e| <~ 7)

// fp32 row -> bf16x8 fragment with scale (weights are L2-hot)
__device__ inline bf16x8 cvt8(const float* p, float s) {
  f32x4 a = *(const f32x4*)p;
  f32x4 b = *(const f32x4*)(p + 4);
  bf16x8 r;
  #pragma unroll
  for (int i = 0; i < 4; ++i) { r[i] = (bf16)(a[i] * s); r[4 + i] = (bf16)(b[i] * s); }
  return r;
}

// ---------------- kernel 1: QKV projections (R16-exact) --------------------
__global__ __launch_bounds__(512) void proj_kernel(
    const float* __restrict__ x, const float* __restrict__ fw,
    const float* __restrict__ wq, const float* __restrict__ wk,
    const float* __restrict__ wv,
    const float* __restrict__ bq, const float* __restrict__ bk,
    const float* __restrict__ bv,
    bf16* __restrict__ Qt, bf16* __restrict__ Kt, bf16* __restrict__ Vt,
    float qscale)
{
  const int wg = blockIdx.x;
  const int b = wg >> 6, tile = wg & 63;
  const int t = threadIdx.x;
  const int w = t >> 6, lane = t & 63, quad = lane >> 4, l15 = lane & 15;

  __shared__ bf16 stage[128 * VS];      // 18432 B; aliases Xt[64][XS] (17408)

  const float* xb = x + (size_t)b * CH * NTOK + tile * 64;
  #pragma unroll
  for (int i = 0; i < 8; ++i) {
    int c = (i * 8 + w) * 2;            // channel pair
    float f0 = fw[c], f1 = fw[c + 1];
    float x0 = xb[(size_t)c * NTOK + lane] * f0;
    float x1 = xb[(size_t)(c + 1) * NTOK + lane] * f1;
    bf16x2 pk; pk.x = (bf16)x0; pk.y = (bf16)x1;
    *(bf16x2*)(&stage[lane * XS + c]) = pk;
  }
  __syncthreads();

  bf16x8 xfrag[4][4];
  #pragma unroll
  for (int st = 0; st < 4; ++st)
    #pragma unroll
    for (int ks = 0; ks < 4; ++ks)
      xfrag[st][ks] = *(const bf16x8*)(&stage[(st * 16 + l15) * XS + ks * 32 + quad * 8]);

  const size_t wrow = (size_t)(w * 16 + l15) * CH;
  const int tokb = tile * 64;
  __syncthreads();                      // all xfrag in regs; stage reusable

  // ---- Q ----
  {
    bf16x8 qw[4];
    #pragma unroll
    for (int ks = 0; ks < 4; ++ks) qw[ks] = cvt8(wq + wrow + ks * 32 + quad * 8, qscale);
    f32x4 acc[4];
    #pragma unroll
    for (int st = 0; st < 4; ++st) acc[st] = (f32x4){0.f, 0.f, 0.f, 0.f};
    #pragma unroll
    for (int ks = 0; ks < 4; ++ks)
      #pragma unroll
      for (int st = 0; st < 4; ++st)
        acc[st] = MFMA16(qw[ks], xfrag[st][ks], acc[st]);
    float bias[4];
    #pragma unroll
    for (int r = 0; r < 4; ++r) bias[r] = bq[w * 16 + quad * 4 + r] * qscale;
    #pragma unroll
    for (int st = 0; st < 4; ++st) {
      bf16x4 o;
      #pragma unroll
      for (int r = 0; r < 4; ++r) o[r] = (bf16)(acc[st][r] + bias[r]);
      *(bf16x4*)(&stage[(st * 16 + l15) * XS + w * 16 + quad * 4]) = o;
    }
    __syncthreads();
    #pragma unroll
    for (int p = 0; p < 2; ++p) {
      int idx = p * 512 + t, row = idx >> 4, ch = (idx & 15) * 8;
      u32x4 d = *(const u32x4*)(&stage[row * XS + ch]);
      *(u32x4*)(&Qt[((size_t)b * NTOK + tokb + row) * CH + ch]) = d;
    }
    __syncthreads();
  }
  // ---- K ----
  {
    bf16x8 kw[4];
    #pragma unroll
    for (int ks = 0; ks < 4; ++ks) kw[ks] = cvt8(wk + wrow + ks * 32 + quad * 8, 1.0f);
    f32x4 acc[4];
    #pragma unroll
    for (int st = 0; st < 4; ++st) acc[st] = (f32x4){0.f, 0.f, 0.f, 0.f};
    #pragma unroll
    for (int ks = 0; ks < 4; ++ks)
      #pragma unroll
      for (int st = 0; st < 4; ++st)
        acc[st] = MFMA16(kw[ks], xfrag[st][ks], acc[st]);
    float bias[4];
    #pragma unroll
    for (int r = 0; r < 4; ++r) bias[r] = bk[w * 16 + quad * 4 + r];
    #pragma unroll
    for (int st = 0; st < 4; ++st) {
      bf16x4 o;
      #pragma unroll
      for (int r = 0; r < 4; ++r) o[r] = (bf16)(acc[st][r] + bias[r]);
      *(bf16x4*)(&stage[(st * 16 + l15) * XS + w * 16 + quad * 4]) = o;
    }
    __syncthreads();
    #pragma unroll
    for (int p = 0; p < 2; ++p) {
      int idx = p * 512 + t, row = idx >> 4, ch = (idx & 15) * 8;
      u32x4 d = *(const u32x4*)(&stage[row * XS + ch]);
      *(u32x4*)(&Kt[((size_t)b * NTOK + tokb + row) * CH + ch]) = d;
    }
    __syncthreads();
  }
  // ---- V ----
  {
    bf16x8 vw[4];
    #pragma unroll
    for (int ks = 0; ks < 4; ++ks) vw[ks] = cvt8(wv + wrow + ks * 32 + quad * 8, 1.0f);
    f32x4 acc[4];
    #pragma unroll
    for (int st = 0; st < 4; ++st) acc[st] = (f32x4){0.f, 0.f, 0.f, 0.f};
    #pragma unroll
    for (int ks = 0; ks < 4; ++ks)
      #pragma unroll
      for (int st = 0; st < 4; ++st)
        acc[st] = MFMA16(xfrag[st][ks], vw[ks], acc[st]);
    float bias = bv[w * 16 + l15];
    #pragma unroll
    for (int st = 0; st < 4; ++st) {
      bf16x4 o;
      #pragma unroll
      for (int r = 0; r < 4; ++r) o[r] = (bf16)(acc[st][r] + bias);
      *(bf16x4*)(&stage[(w * 16 + l15) * VS + st * 16 + quad * 4]) = o;
    }
    __syncthreads();
    #pragma unroll
    for (int p = 0; p < 2; ++p) {
      int idx = p * 512 + t, row = idx >> 3, tk = (idx & 7) * 8;
      u32x4 d = *(const u32x4*)(&stage[row * VS + tk]);
      *(u32x4*)(&Vt[((size_t)b * CH + row) * NTOK + tokb + tk]) = d;
    }
  }
}

// ---------------- kernel 2: flash partial (R16 base + addr-hoist + T5) -----
// Grid 512 = b(8) x half(2) x qt128(32). q=32/wave. LDS 50176 B.
__global__ __launch_bounds__(256, 2) void flash_part_kernel(
    const bf16* __restrict__ Qt, const bf16* __restrict__ Kt,
    const bf16* __restrict__ Vt, f16* __restrict__ Op, float* __restrict__ Lp)
{
  const int wg = blockIdx.x;
  const int b = wg >> 6, half = (wg >> 5) & 1, qt = wg & 31;
  const int t = threadIdx.x;
  const int w = t >> 6, lane = t & 63, quad = lane >> 4, l15 = lane & 15;
  const int swz = l15 & 7;

  __shared__ bf16 ldsK[64 * 128];       // [kv][c], 16B-block ^= row&7
  __shared__ bf16 ldsV[128 * 64];       // [c][kv], 16B-block ^= row&7
  __shared__ bf16 ldsP[4 * 32 * PS];    // per-wave [q32][kv64], stride 72

  bf16x8 qfrag[2][4];
  #pragma unroll
  for (int s2 = 0; s2 < 2; ++s2) {
    const bf16* qb = Qt + ((size_t)b * NTOK + qt * 128 + w * 32 + s2 * 16 + l15) * CH;
    #pragma unroll
    for (int ks = 0; ks < 4; ++ks)
      qfrag[s2][ks] = *(const bf16x8*)(qb + ks * 32 + quad * 8);
  }

  f32x4 o_acc[2][8];
  #pragma unroll
  for (int s2 = 0; s2 < 2; ++s2)
    #pragma unroll
    for (int nt = 0; nt < 8; ++nt) o_acc[s2][nt] = (f32x4){0.f, 0.f, 0.f, 0.f};
  float lsum[2] = {0.f, 0.f};

  const bf16* kb = Kt + ((size_t)b * NTOK + half * 2048) * CH;
  const bf16* vb = Vt + (size_t)b * CH * NTOK + half * 2048;
  bf16* Pw = ldsP + w * 32 * PS;

  const bf16* kg[4]; bf16* kl[4];
  const bf16* vg[4]; bf16* vl[4];
  #pragma unroll
  for (int i = 0; i < 4; ++i) {
    int idx = t + i * 256;
    { int row = idx >> 4, cb = idx & 15;
      kg[i] = kb + (size_t)idx * 8;
      kl[i] = &ldsK[row * 128 + ((cb ^ (row & 7)) * 8)]; }
    { int row = idx >> 3, cb = idx & 7;
      vg[i] = vb + (size_t)row * NTOK + cb * 8;
      vl[i] = &ldsV[row * 64 + ((cb ^ (row & 7)) * 8)]; }
  }

  // hoisted loop-invariant LDS addresses: strip indices become ds-offset
  // immediates (mt: +4096 B, nt: +2048 B, s2: +2304 B -- all < 64 KiB)
  const bf16* kfb[4];
  #pragma unroll
  for (int ks = 0; ks < 4; ++ks)
    kfb[ks] = &ldsK[l15 * 128 + (((ks * 4 + quad) ^ swz) * 8)];
  const bf16* vfb[2];
  #pragma unroll
  for (int k2 = 0; k2 < 2; ++k2)
    vfb[k2] = &ldsV[l15 * 64 + (((k2 * 4 + quad) ^ swz) * 8)];
  bf16* pwb = &Pw[l15 * PS + quad * 4];
  const bf16* prb = &Pw[l15 * PS + quad * 8];

  // async-STAGE prologue: tile 0 -> registers (T14)
  u32x4 rk[4], rv[4];
  #pragma unroll
  for (int i = 0; i < 4; ++i) {
    rk[i] = *(const u32x4*)kg[i];
    rv[i] = *(const u32x4*)vg[i];
    kg[i] += 64 * CH;                   // next 64-kv tile of K
    vg[i] += 64;                        // next 64-kv slab of V^T
  }

  for (int kt = 0; kt < 32; ++kt) {
    __syncthreads();                    // prev iter's LDS readers done
    #pragma unroll
    for (int i = 0; i < 4; ++i) {       // regs -> LDS only (loads landed long ago)
      *(u32x4*)kl[i] = rk[i];
      *(u32x4*)vl[i] = rv[i];
    }
    __syncthreads();

    // issue NEXT tile's global loads now; latency hides under this tile's
    // MFMA+exp2. vmcnt waits at next iter's LDS stores.
    if (kt < 31) {
      #pragma unroll
      for (int i = 0; i < 4; ++i) {
        rk[i] = *(const u32x4*)kg[i];
        rv[i] = *(const u32x4*)vg[i];
        kg[i] += 64 * CH;
        vg[i] += 64;
      }
    }

    // S^T = K Q^T (qscale*L2E folded into Wq); per 16-kv strip mt
    #pragma unroll
    for (int mt = 0; mt < 4; ++mt) {
      f32x4 s[2];
      s[0] = (f32x4){0.f, 0.f, 0.f, 0.f};
      s[1] = (f32x4){0.f, 0.f, 0.f, 0.f};
      __builtin_amdgcn_s_setprio(1);    // T5: favor MFMA cluster
      #pragma unroll
      for (int ks = 0; ks < 4; ++ks) {
        bf16x8 kfr = *(const bf16x8*)(kfb[ks] + mt * 2048);
        s[0] = MFMA16(kfr, qfrag[0][ks], s[0]);
        s[1] = MFMA16(kfr, qfrag[1][ks], s[1]);
      }
      __builtin_amdgcn_s_setprio(0);
      // p = exp2(s - 8): per-lane; P write b64 (kv quad*4..+3 contiguous)
      #pragma unroll
      for (int s2 = 0; s2 < 2; ++s2) {
        f32x4 v = s[s2];
        bf16x4 pk;
        float ps = 0.f;
        #pragma unroll
        for (int r = 0; r < 4; ++r) {
          float p = exp2f(v[r] - FIXM);
          ps += p;
          pk[r] = (bf16)p;
        }
        lsum[s2] += ps;
        *(bf16x4*)(pwb + s2 * 16 * PS + mt * 16) = pk;
      }
    }
    // P wave-private: wave-internal lgkmcnt orders write->read (no barrier)

    bf16x8 pfrag[2][2];
    #pragma unroll
    for (int s2 = 0; s2 < 2; ++s2)
      #pragma unroll
      for (int c = 0; c < 2; ++c)
        pfrag[s2][c] = *(const bf16x8*)(prb + s2 * 16 * PS + c * 32);

    // O += P V  (V frags shared across both q subtiles)
    __builtin_amdgcn_s_setprio(1);
    #pragma unroll
    for (int k2 = 0; k2 < 2; ++k2)
      #pragma unroll
      for (int nt = 0; nt < 8; ++nt) {
        bf16x8 vfr = *(const bf16x8*)(vfb[k2] + nt * 1024);
        o_acc[0][nt] = MFMA16(pfrag[0][k2], vfr, o_acc[0][nt]);
        o_acc[1][nt] = MFMA16(pfrag[1][k2], vfr, o_acc[1][nt]);
      }
    __builtin_amdgcn_s_setprio(0);
  }

  // write unnormalized partial O (fp16) + partial row sums
  const size_t obase = ((size_t)(b * 2 + half) * NTOK + qt * 128 + w * 32) * CH;
  #pragma unroll
  for (int s2 = 0; s2 < 2; ++s2)
    #pragma unroll
    for (int nt = 0; nt < 8; ++nt)
      #pragma unroll
      for (int r = 0; r < 4; ++r) {
        int row = s2 * 16 + quad * 4 + r;
        Op[obase + (size_t)row * CH + nt * 16 + l15] = (f16)o_acc[s2][nt][r];
      }
  #pragma unroll
  for (int s2 = 0; s2 < 2; ++s2) {
    float v = lsum[s2];
    v += __shfl_xor(v, 16);
    v += __shfl_xor(v, 32);
    if (quad == 0)
      Lp[(size_t)(b * 2 + half) * NTOK + qt * 128 + w * 32 + s2 * 16 + l15] = v;
  }
}

// ---------------- kernel 3: merge halves + Wo projection (R16-exact) -------
__global__ __launch_bounds__(256) void merge_kernel(
    const f16* __restrict__ Op, const float* __restrict__ Lp,
    const float* __restrict__ wo, const float* __restrict__ bo,
    float* __restrict__ out)
{
  const int wg = blockIdx.x;            // 512 = b(8) x tile(64)
  const int b = wg >> 6, tile = wg & 63;
  const int t = threadIdx.x;
  const int w = t >> 6, lane = t & 63, quad = lane >> 4, l15 = lane & 15;

  __shared__ bf16 ldsO[64 * MS];        // [tok][c], padded stride (272 B)

  const f16* o0 = Op + ((size_t)(b * 2 + 0) * NTOK + tile * 64) * CH;
  const f16* o1 = Op + ((size_t)(b * 2 + 1) * NTOK + tile * 64) * CH;
  const float* lp0 = Lp + (size_t)(b * 2 + 0) * NTOK + tile * 64;
  const float* lp1 = Lp + (size_t)(b * 2 + 1) * NTOK + tile * 64;

  #pragma unroll
  for (int i = 0; i < 4; ++i) {
    int idx = t + i * 256;              // 1024 chunks of 8 elems
    int row = idx >> 4, cb = idx & 15;
    float inv = 1.0f / (lp0[row] + lp1[row]);
    f16x8 a0 = *(const f16x8*)(o0 + (size_t)row * CH + cb * 8);
    f16x8 a1 = *(const f16x8*)(o1 + (size_t)row * CH + cb * 8);
    bf16 tmp[8];
    #pragma unroll
    for (int j = 0; j < 8; ++j)
      tmp[j] = (bf16)(((float)a0[j] + (float)a1[j]) * inv);
    *(u32x4*)(&ldsO[row * MS + cb * 8]) = *(u32x4*)tmp;
  }
  __syncthreads();

  #pragma unroll
  for (int mi = 0; mi < 2; ++mi) {
    int mt = w * 2 + mi;
    f32x4 facc[4];
    #pragma unroll
    for (int nt = 0; nt < 4; ++nt) facc[nt] = (f32x4){0.f, 0.f, 0.f, 0.f};
    #pragma unroll
    for (int ks = 0; ks < 4; ++ks) {
      bf16x8 afr = cvt8(wo + (size_t)(mt * 16 + l15) * CH + ks * 32 + quad * 8, 1.0f);
      #pragma unroll
      for (int nt = 0; nt < 4; ++nt) {
        bf16x8 bfr = *(const bf16x8*)(&ldsO[(nt * 16 + l15) * MS + ks * 32 + quad * 8]);
        facc[nt] = MFMA16(afr, bfr, facc[nt]);
      }
    }
    #pragma unroll
    for (int nt = 0; nt < 4; ++nt) {
      int n = tile * 64 + nt * 16 + l15;
      #pragma unroll
      for (int r = 0; r < 4; ++r) {
        int o = mt * 16 + quad * 4 + r;
        out[((size_t)b * CH + o) * NTOK + n] = facc[nt][r] + bo[o];
      }
    }
  }
}

// ---------------- launch ---------------------------------------------------
extern "C" void kernel_launch(void* const* d_in, const int* in_sizes, int n_in,
                              void* d_out, int out_size, void* d_ws, size_t ws_size,
                              hipStream_t stream)
{
  const float* x  = (const float*)d_in[0];
  const float* fw = (const float*)d_in[1];
  const float* wq = (const float*)d_in[2];
  const float* bq = (const float*)d_in[3];
  const float* wk = (const float*)d_in[4];
  const float* bk = (const float*)d_in[5];
  const float* wv = (const float*)d_in[6];
  const float* bv = (const float*)d_in[7];
  const float* wo = (const float*)d_in[8];
  const float* bo = (const float*)d_in[9];
  float* out = (float*)d_out;

  char* ws = (char*)d_ws;
  bf16*  Qt  = (bf16*)ws;                              // 8 MB
  bf16*  Kt  = Qt + (size_t)BATCH * NTOK * CH;         // 8 MB
  bf16*  Vt  = Kt + (size_t)BATCH * NTOK * CH;         // 8 MB
  f16*   Op  = (f16*)(ws + 3ull * 8388608);            // 16 MB: [2B][N][C] fp16
  float* Lp  = (float*)((char*)Op + 16777216);         // 256 KB

  // 1/sqrt(128) * log2(e): exp2-domain scale folded into Wq/bq
  const float qscale = 0.08838834764831845f * 1.44269504f;

  proj_kernel<<<512, 512, 0, stream>>>(x, fw, wq, wk, wv,
                                       bq, bk, bv, Qt, Kt, Vt, qscale);
  flash_part_kernel<<<512, 256, 0, stream>>>(Qt, Kt, Vt, Op, Lp);
  merge_kernel<<<512, 256, 0, stream>>>(Op, Lp, wo, bo, out);
}

// Round 13
// 193.508 us; speedup vs baseline: 1.4577x; 1.0206x over previous
//
#include <hip/hip_runtime.h>
#include <hip/hip_bf16.h>
#include <math.h>

// FrequencySelfAttention3: B=8, C=128, H=W=64 (N=4096 tokens).
// ifft2(|F|·w_c·e^{i·angle F}) = w_c·x  -> FFT branch is a per-channel scale.
// R20: flash restructure for LDS-issue volume. Pipe arithmetic: 44 b128 LDS
// ops/wave/iter x 8 waves on one LDS pipe ~ 3-4.6K cyc/iter >> matrix pipe
// ~620 -- LDS issue + serial chain bound (VALU hoist was null in R19: the
// compiler had already folded addresses). Fix: q=64/wave (4 subtiles, same
// proven 16x16 fragment paths), WG q=256, kv QUARTERS (S=4 slab merge =
// R13/R14-proven). Per-wave-iter LDS reads 36->20 b128 at same MFMA count.
// Staging: global_load_lds DMA (frees T14's 32 prefetch VGPRs -- needed for
// o_acc 128 + qfrag 64), kv=32 tiles double-buffered, swizzle applied on
// the GLOBAL source (m173: DMA dest must be linear); K keeps XOR-8, V uses
// additive block rotation (2-way clean). ONE barrier/iter (drain at barrier
// covers the DMA issued at iter top -> latency hidden under compute).
// Proj = R16-exact. Merge = R13's nslab merge (measured ~7us).

typedef __bf16 bf16;
typedef _Float16 f16;
typedef __bf16 bf16x8 __attribute__((ext_vector_type(8)));
typedef __bf16 bf16x4 __attribute__((ext_vector_type(4)));
typedef __bf16 bf16x2 __attribute__((ext_vector_type(2)));
typedef _Float16 f16x8 __attribute__((ext_vector_type(8)));
typedef float  f32x4  __attribute__((ext_vector_type(4)));
typedef unsigned int u32x4 __attribute__((ext_vector_type(4)));

#define MFMA16(a, b, c) __builtin_amdgcn_mfma_f32_16x16x32_bf16((a), (b), (c), 0, 0, 0)

static constexpr int BATCH = 8;
static constexpr int CH    = 128;
static constexpr int NTOK  = 4096;
static constexpr int XS    = 136;   // proj stage stride (bf16 elems)
static constexpr int VS    = 72;    // proj V-stage stride
static constexpr int PS2   = 40;    // flash P stride (80 B, 16B-aligned)
static constexpr int MS    = 136;   // merge O row stride
static constexpr float FIXM = 8.0f; // fixed max, exp2 domain (|S*log2e| <~ 7)

// async global->LDS DMA, 16B per lane; dest = wave-uniform base + lane*16
__device__ inline void dma16(const bf16* g, bf16* l) {
  __builtin_amdgcn_global_load_lds(
      (__attribute__((address_space(1))) unsigned int*)g,
      (__attribute__((address_space(3))) unsigned int*)l, 16, 0, 0);
}

// fp32 row -> bf16x8 fragment with scale (weights are L2-hot)
__device__ inline bf16x8 cvt8(const float* p, float s) {
  f32x4 a = *(const f32x4*)p;
  f32x4 b = *(const f32x4*)(p + 4);
  bf16x8 r;
  #pragma unroll
  for (int i = 0; i < 4; ++i) { r[i] = (bf16)(a[i] * s); r[4 + i] = (bf16)(b[i] * s); }
  return r;
}

// ---------------- kernel 1: QKV projections (R16-exact) --------------------
__global__ __launch_bounds__(512) void proj_kernel(
    const float* __restrict__ x, const float* __restrict__ fw,
    const float* __restrict__ wq, const float* __restrict__ wk,
    const float* __restrict__ wv,
    const float* __restrict__ bq, const float* __restrict__ bk,
    const float* __restrict__ bv,
    bf16* __restrict__ Qt, bf16* __restrict__ Kt, bf16* __restrict__ Vt,
    float qscale)
{
  const int wg = blockIdx.x;
  const int b = wg >> 6, tile = wg & 63;
  const int t = threadIdx.x;
  const int w = t >> 6, lane = t & 63, quad = lane >> 4, l15 = lane & 15;

  __shared__ bf16 stage[128 * VS];      // 18432 B; aliases Xt[64][XS] (17408)

  const float* xb = x + (size_t)b * CH * NTOK + tile * 64;
  #pragma unroll
  for (int i = 0; i < 8; ++i) {
    int c = (i * 8 + w) * 2;            // channel pair
    float f0 = fw[c], f1 = fw[c + 1];
    float x0 = xb[(size_t)c * NTOK + lane] * f0;
    float x1 = xb[(size_t)(c + 1) * NTOK + lane] * f1;
    bf16x2 pk; pk.x = (bf16)x0; pk.y = (bf16)x1;
    *(bf16x2*)(&stage[lane * XS + c]) = pk;
  }
  __syncthreads();

  bf16x8 xfrag[4][4];
  #pragma unroll
  for (int st = 0; st < 4; ++st)
    #pragma unroll
    for (int ks = 0; ks < 4; ++ks)
      xfrag[st][ks] = *(const bf16x8*)(&stage[(st * 16 + l15) * XS + ks * 32 + quad * 8]);

  const size_t wrow = (size_t)(w * 16 + l15) * CH;
  const int tokb = tile * 64;
  __syncthreads();                      // all xfrag in regs; stage reusable

  // ---- Q ----
  {
    bf16x8 qw[4];
    #pragma unroll
    for (int ks = 0; ks < 4; ++ks) qw[ks] = cvt8(wq + wrow + ks * 32 + quad * 8, qscale);
    f32x4 acc[4];
    #pragma unroll
    for (int st = 0; st < 4; ++st) acc[st] = (f32x4){0.f, 0.f, 0.f, 0.f};
    #pragma unroll
    for (int ks = 0; ks < 4; ++ks)
      #pragma unroll
      for (int st = 0; st < 4; ++st)
        acc[st] = MFMA16(qw[ks], xfrag[st][ks], acc[st]);
    float bias[4];
    #pragma unroll
    for (int r = 0; r < 4; ++r) bias[r] = bq[w * 16 + quad * 4 + r] * qscale;
    #pragma unroll
    for (int st = 0; st < 4; ++st) {
      bf16x4 o;
      #pragma unroll
      for (int r = 0; r < 4; ++r) o[r] = (bf16)(acc[st][r] + bias[r]);
      *(bf16x4*)(&stage[(st * 16 + l15) * XS + w * 16 + quad * 4]) = o;
    }
    __syncthreads();
    #pragma unroll
    for (int p = 0; p < 2; ++p) {
      int idx = p * 512 + t, row = idx >> 4, ch = (idx & 15) * 8;
      u32x4 d = *(const u32x4*)(&stage[row * XS + ch]);
      *(u32x4*)(&Qt[((size_t)b * NTOK + tokb + row) * CH + ch]) = d;
    }
    __syncthreads();
  }
  // ---- K ----
  {
    bf16x8 kw[4];
    #pragma unroll
    for (int ks = 0; ks < 4; ++ks) kw[ks] = cvt8(wk + wrow + ks * 32 + quad * 8, 1.0f);
    f32x4 acc[4];
    #pragma unroll
    for (int st = 0; st < 4; ++st) acc[st] = (f32x4){0.f, 0.f, 0.f, 0.f};
    #pragma unroll
    for (int ks = 0; ks < 4; ++ks)
      #pragma unroll
      for (int st = 0; st < 4; ++st)
        acc[st] = MFMA16(kw[ks], xfrag[st][ks], acc[st]);
    float bias[4];
    #pragma unroll
    for (int r = 0; r < 4; ++r) bias[r] = bk[w * 16 + quad * 4 + r];
    #pragma unroll
    for (int st = 0; st < 4; ++st) {
      bf16x4 o;
      #pragma unroll
      for (int r = 0; r < 4; ++r) o[r] = (bf16)(acc[st][r] + bias[r]);
      *(bf16x4*)(&stage[(st * 16 + l15) * XS + w * 16 + quad * 4]) = o;
    }
    __syncthreads();
    #pragma unroll
    for (int p = 0; p < 2; ++p) {
      int idx = p * 512 + t, row = idx >> 4, ch = (idx & 15) * 8;
      u32x4 d = *(const u32x4*)(&stage[row * XS + ch]);
      *(u32x4*)(&Kt[((size_t)b * NTOK + tokb + row) * CH + ch]) = d;
    }
    __syncthreads();
  }
  // ---- V ----
  {
    bf16x8 vw[4];
    #pragma unroll
    for (int ks = 0; ks < 4; ++ks) vw[ks] = cvt8(wv + wrow + ks * 32 + quad * 8, 1.0f);
    f32x4 acc[4];
    #pragma unroll
    for (int st = 0; st < 4; ++st) acc[st] = (f32x4){0.f, 0.f, 0.f, 0.f};
    #pragma unroll
    for (int ks = 0; ks < 4; ++ks)
      #pragma unroll
      for (int st = 0; st < 4; ++st)
        acc[st] = MFMA16(xfrag[st][ks], vw[ks], acc[st]);
    float bias = bv[w * 16 + l15];
    #pragma unroll
    for (int st = 0; st < 4; ++st) {
      bf16x4 o;
      #pragma unroll
      for (int r = 0; r < 4; ++r) o[r] = (bf16)(acc[st][r] + bias);
      *(bf16x4*)(&stage[(w * 16 + l15) * VS + st * 16 + quad * 4]) = o;
    }
    __syncthreads();
    #pragma unroll
    for (int p = 0; p < 2; ++p) {
      int idx = p * 512 + t, row = idx >> 3, tk = (idx & 7) * 8;
      u32x4 d = *(const u32x4*)(&stage[row * VS + tk]);
      *(u32x4*)(&Vt[((size_t)b * CH + row) * NTOK + tokb + tk]) = d;
    }
  }
}

// ---------------- kernel 2: flash partial, q=64/wave, DMA-dbuf kv=32 -------
// Grid = b(8) x slab(S) x qt256(16). 256 thr / 4 waves, each wave q=64.
// LDS 53248: buf0 {K 8K | V 8K} buf1 {K 8K | V 8K} P 20K. ntile kt-iters.
__global__ __launch_bounds__(256, 2) void flash_part_kernel(
    const bf16* __restrict__ Qt, const bf16* __restrict__ Kt,
    const bf16* __restrict__ Vt, f16* __restrict__ Op, float* __restrict__ Lp,
    int nslab, int ntile)
{
  __shared__ __align__(16) char lds[53248];

  const int wg = blockIdx.x;
  const int qt = wg & 15;
  const int slab = (wg >> 4) % nslab;
  const int b = wg / (nslab * 16);
  const int t = threadIdx.x;
  const int w = t >> 6, lane = t & 63, quad = lane >> 4, l15 = lane & 15;
  const int swz = l15 & 7;

  // persistent Q fragments: 64 q-rows per wave (4 subtiles of 16)
  bf16x8 qfrag[4][4];
  #pragma unroll
  for (int s4 = 0; s4 < 4; ++s4) {
    const bf16* qb = Qt + ((size_t)b * NTOK + qt * 256 + w * 64 + s4 * 16 + l15) * CH;
    #pragma unroll
    for (int ks = 0; ks < 4; ++ks)
      qfrag[s4][ks] = *(const bf16x8*)(qb + ks * 32 + quad * 8);
  }

  f32x4 o_acc[4][8];
  #pragma unroll
  for (int s4 = 0; s4 < 4; ++s4)
    #pragma unroll
    for (int nt = 0; nt < 8; ++nt) o_acc[s4][nt] = (f32x4){0.f, 0.f, 0.f, 0.f};
  float lsum[4] = {0.f, 0.f, 0.f, 0.f};

  const int koff = slab * ntile * 32;   // kv offset of this slab
  const bf16* kb = Kt + ((size_t)b * NTOK + koff) * CH;
  const bf16* vb = Vt + (size_t)b * CH * NTOK + koff;

  // DMA sources: pre-swizzled GLOBAL addresses, linear LDS dest (m173).
  // K slot(row 0..31, cb 0..15): LDS row*256B+cb*16B holds K[row][(cb^(row&7))*8..+8]
  // V slot(ch 0..127, cb 0..3): LDS ch*64B+cb*16B holds V[ch][kvb*8..+8],
  //   kvb = (cb + ((ch>>2)&3)) & 3  (additive rotation, 2-way-clean reads)
  const bf16* kdma[2]; const bf16* vdma[2];
  #pragma unroll
  for (int jj = 0; jj < 2; ++jj) {
    int slot = w * 128 + jj * 64 + lane;
    int krow = slot >> 4, kcb = slot & 15;
    kdma[jj] = kb + (size_t)krow * CH + ((kcb ^ (krow & 7)) * 8);
    int vch = slot >> 2, vcb = slot & 3;
    vdma[jj] = vb + (size_t)vch * NTOK + (((vcb + ((vch >> 2) & 3)) & 3) * 8);
  }

  bf16* Pw = (bf16*)(lds + 32768) + w * 64 * PS2;   // per-wave [64 q][PS2]

  // prologue: DMA tile 0 -> buffer 0 (barrier drains vmcnt incl. qfrag)
  {
    bf16* dK = (bf16*)(lds) + w * 1024;             // ops 2w,2w+1: 1KB each
    bf16* dV = (bf16*)(lds + 8192) + w * 1024;
    dma16(kdma[0], dK); dma16(kdma[1], dK + 512);
    dma16(vdma[0], dV); dma16(vdma[1], dV + 512);
    kdma[0] += 32 * CH; kdma[1] += 32 * CH;
    vdma[0] += 32;      vdma[1] += 32;
  }
  __syncthreads();

  for (int kt = 0; kt < ntile; ++kt) {
    const char* bK = lds + ((kt & 1) ? 16384 : 0);
    const char* bV = bK + 8192;

    // issue next tile's DMA into the other buffer; latency hides under
    // this tile's compute, drained by the barrier at loop end.
    if (kt + 1 < ntile) {
      bf16* nK = (bf16*)(lds + ((kt & 1) ? 0 : 16384)) + w * 1024;
      bf16* nV = nK + 4096;             // +8192 B = V region of that buffer
      dma16(kdma[0], nK); dma16(kdma[1], nK + 512);
      dma16(vdma[0], nV); dma16(vdma[1], nV + 512);
      kdma[0] += 32 * CH; kdma[1] += 32 * CH;
      vdma[0] += 32;      vdma[1] += 32;
    }

    // ---- S^T = K Q^T per 16-kv strip; exp2 -> P (K-frag shared by 4 s4) --
    #pragma unroll
    for (int mt = 0; mt < 2; ++mt) {
      f32x4 s[4];
      #pragma unroll
      for (int s4 = 0; s4 < 4; ++s4) s[s4] = (f32x4){0.f, 0.f, 0.f, 0.f};
      #pragma unroll
      for (int ks = 0; ks < 4; ++ks) {
        bf16x8 kfr = *(const bf16x8*)(bK + (mt * 16 + l15) * 256 + (((ks * 4 + quad) ^ swz) * 16));
        #pragma unroll
        for (int s4 = 0; s4 < 4; ++s4)
          s[s4] = MFMA16(kfr, qfrag[s4][ks], s[s4]);
      }
      #pragma unroll
      for (int s4 = 0; s4 < 4; ++s4) {
        f32x4 v = s[s4];
        bf16x4 pk; float ps = 0.f;
        #pragma unroll
        for (int r = 0; r < 4; ++r) {
          float p = exp2f(v[r] - FIXM);
          ps += p; pk[r] = (bf16)p;
        }
        lsum[s4] += ps;
        *(bf16x4*)(Pw + (s4 * 16 + l15) * PS2 + mt * 16 + quad * 4) = pk;
      }
    }
    // P wave-private: wave-internal lgkmcnt orders write->read (no barrier)

    // ---- O += P V (V-frag shared by 4 s4) ----
    bf16x8 pfrag[4];
    #pragma unroll
    for (int s4 = 0; s4 < 4; ++s4)
      pfrag[s4] = *(const bf16x8*)(Pw + (s4 * 16 + l15) * PS2 + quad * 8);
    const int vrot = (l15 >> 2) & 3;
    const char* vrb = bV + l15 * 64 + (((quad - vrot) & 3) * 16);
    #pragma unroll
    for (int nt = 0; nt < 8; ++nt) {
      bf16x8 vfr = *(const bf16x8*)(vrb + nt * 1024);
      #pragma unroll
      for (int s4 = 0; s4 < 4; ++s4)
        o_acc[s4][nt] = MFMA16(pfrag[s4], vfr, o_acc[s4][nt]);
    }

    __syncthreads();                    // drains vmcnt (next tile landed)
  }

  // write unnormalized partial O (fp16, plain stores) + partial row sums
  const size_t obase = ((size_t)(slab * BATCH + b) * NTOK + qt * 256 + w * 64) * CH;
  #pragma unroll
  for (int s4 = 0; s4 < 4; ++s4)
    #pragma unroll
    for (int nt = 0; nt < 8; ++nt)
      #pragma unroll
      for (int r = 0; r < 4; ++r) {
        int row = s4 * 16 + quad * 4 + r;
        Op[obase + (size_t)row * CH + nt * 16 + l15] = (f16)o_acc[s4][nt][r];
      }
  #pragma unroll
  for (int s4 = 0; s4 < 4; ++s4) {
    float v = lsum[s4];
    v += __shfl_xor(v, 16);
    v += __shfl_xor(v, 32);
    if (quad == 0)
      Lp[(size_t)(slab * BATCH + b) * NTOK + qt * 256 + w * 64 + s4 * 16 + l15] = v;
  }
}

// ---------------- kernel 3: merge S slabs + Wo projection (R13-proven) -----
__global__ __launch_bounds__(256) void merge_kernel(
    const f16* __restrict__ Op, const float* __restrict__ Lp,
    const float* __restrict__ wo, const float* __restrict__ bo,
    float* __restrict__ out, int nslab)
{
  const int wg = blockIdx.x;            // 512 = b(8) x tile(64)
  const int b = wg >> 6, tile = wg & 63;
  const int t = threadIdx.x;
  const int w = t >> 6, lane = t & 63, quad = lane >> 4, l15 = lane & 15;

  __shared__ bf16 ldsO[64 * MS];        // [tok][c], padded stride (272 B)

  const size_t slabO = (size_t)BATCH * NTOK * CH;   // f16 elems per slab
  const size_t slabL = (size_t)BATCH * NTOK;
  const f16* ob = Op + ((size_t)b * NTOK + tile * 64) * CH;
  const float* lp = Lp + (size_t)b * NTOK + tile * 64;

  #pragma unroll
  for (int i = 0; i < 4; ++i) {
    int idx = t + i * 256;              // 1024 chunks of 8 elems
    int row = idx >> 4, cb = idx & 15;
    float lsum_ = 0.f;
    for (int s = 0; s < nslab; ++s) lsum_ += lp[s * slabL + row];
    float acc8[8] = {0.f, 0.f, 0.f, 0.f, 0.f, 0.f, 0.f, 0.f};
    for (int s = 0; s < nslab; ++s) {
      f16x8 a = *(const f16x8*)(ob + s * slabO + (size_t)row * CH + cb * 8);
      #pragma unroll
      for (int j = 0; j < 8; ++j) acc8[j] += (float)a[j];
    }
    float inv = 1.0f / lsum_;
    bf16 tmp[8];
    #pragma unroll
    for (int j = 0; j < 8; ++j) tmp[j] = (bf16)(acc8[j] * inv);
    *(u32x4*)(&ldsO[row * MS + cb * 8]) = *(u32x4*)tmp;
  }
  __syncthreads();

  #pragma unroll
  for (int mi = 0; mi < 2; ++mi) {
    int mt = w * 2 + mi;
    f32x4 facc[4];
    #pragma unroll
    for (int nt = 0; nt < 4; ++nt) facc[nt] = (f32x4){0.f, 0.f, 0.f, 0.f};
    #pragma unroll
    for (int ks = 0; ks < 4; ++ks) {
      bf16x8 afr = cvt8(wo + (size_t)(mt * 16 + l15) * CH + ks * 32 + quad * 8, 1.0f);
      #pragma unroll
      for (int nt = 0; nt < 4; ++nt) {
        bf16x8 bfr = *(const bf16x8*)(&ldsO[(nt * 16 + l15) * MS + ks * 32 + quad * 8]);
        facc[nt] = MFMA16(afr, bfr, facc[nt]);
      }
    }
    #pragma unroll
    for (int nt = 0; nt < 4; ++nt) {
      int n = tile * 64 + nt * 16 + l15;
      #pragma unroll
      for (int r = 0; r < 4; ++r) {
        int o = mt * 16 + quad * 4 + r;
        out[((size_t)b * CH + o) * NTOK + n] = facc[nt][r] + bo[o];
      }
    }
  }
}

// ---------------- launch ---------------------------------------------------
extern "C" void kernel_launch(void* const* d_in, const int* in_sizes, int n_in,
                              void* d_out, int out_size, void* d_ws, size_t ws_size,
                              hipStream_t stream)
{
  const float* x  = (const float*)d_in[0];
  const float* fw = (const float*)d_in[1];
  const float* wq = (const float*)d_in[2];
  const float* bq = (const float*)d_in[3];
  const float* wk = (const float*)d_in[4];
  const float* bk = (const float*)d_in[5];
  const float* wv = (const float*)d_in[6];
  const float* bv = (const float*)d_in[7];
  const float* wo = (const float*)d_in[8];
  const float* bo = (const float*)d_in[9];
  float* out = (float*)d_out;

  char* ws = (char*)d_ws;
  bf16*  Qt  = (bf16*)ws;                              // 8 MB
  bf16*  Kt  = Qt + (size_t)BATCH * NTOK * CH;         // 8 MB
  bf16*  Vt  = Kt + (size_t)BATCH * NTOK * CH;         // 8 MB
  f16*   Op  = (f16*)(ws + 3ull * 8388608);            // S x 8 MB fp16 slabs

  // S=4 (kv quarters, grid 512 = 2 WG/CU one pass) if ws allows, else S=2.
  const size_t qkv_bytes = 3ull * 8388608;
  const size_t need4 = qkv_bytes + 4ull * ((size_t)BATCH * NTOK * CH * 2 + (size_t)BATCH * NTOK * 4);
  const int S = (ws_size >= need4) ? 4 : 2;
  const int ntile = (NTOK / S) / 32;                   // kv-32 tiles per slab

  float* Lp = (float*)((char*)Op + (size_t)S * BATCH * NTOK * CH * 2);

  // 1/sqrt(128) * log2(e): exp2-domain scale folded into Wq/bq
  const float qscale = 0.08838834764831845f * 1.44269504f;

  proj_kernel<<<512, 512, 0, stream>>>(x, fw, wq, wk, wv,
                                       bq, bk, bv, Qt, Kt, Vt, qscale);
  flash_part_kernel<<<BATCH * S * 16, 256, 0, stream>>>(Qt, Kt, Vt, Op, Lp,
                                                        S, ntile);
  merge_kernel<<<512, 256, 0, stream>>>(Op, Lp, wo, bo, out, S);
}